// Round 12
// baseline (153.578 us; speedup 1.0000x reference)
//
#include <hip/hip_runtime.h>

#define SEQ   1024
#define HEADS 12
#define CDIM  768
#define BATCH 8

// 0.125 * log2(e): folds the 1/sqrt(64) score scale and the exp->exp2 change
#define QSCALE 0.18033688011112042f

typedef __attribute__((ext_vector_type(8))) short bf16x8;
typedef __attribute__((ext_vector_type(4))) float f32x4;
typedef __attribute__((ext_vector_type(16))) float f32x16;
typedef __attribute__((ext_vector_type(4))) float float4v;
typedef __attribute__((ext_vector_type(4))) short short4v;

__device__ __forceinline__ void gload_lds16(const void* g, void* l) {
  __builtin_amdgcn_global_load_lds(
      (const __attribute__((address_space(1))) unsigned int*)g,
      (__attribute__((address_space(3))) unsigned int*)l, 16, 0, 0);
}

__device__ __forceinline__ unsigned short f2bf(float f) {
  union { float f; unsigned u; } v; v.f = f;
  unsigned r = v.u + 0x7fff + ((v.u >> 16) & 1);
  return (unsigned short)(r >> 16);
}

// pack two f32 -> u32 of 2x bf16 (lo = a, hi = b); no builtin on gfx950
__device__ __forceinline__ unsigned cvtpk(float a, float b) {
  unsigned r;
  asm("v_cvt_pk_bf16_f32 %0, %1, %2" : "=v"(r) : "v"(a), "v"(b));
  return r;
}

// select bf16 half of a packed u32 as f32 (odd -> high half, even -> low)
__device__ __forceinline__ float bfsel(unsigned u, int odd) {
  union { unsigned u; float f; } v;
  v.u = odd ? (u & 0xffff0000u) : (u << 16);
  return v.f;
}

// x [8192,768] f32 -> A [8192,768] bf16
__global__ __launch_bounds__(256) void prep_x_kernel(const float* __restrict__ x,
                                                     short* __restrict__ A) {
  int i = blockIdx.x * 256 + threadIdx.x;
  int r = i / 192;
  int c4 = (i % 192) * 4;
  float4v xv = *(const float4v*)(x + (size_t)r * 768 + c4);
  short4v hi;
#pragma unroll
  for (int j = 0; j < 4; ++j) hi[j] = (short)f2bf(xv[j]);
  *(short4v*)(A + (size_t)r * 768 + c4) = hi;
}

// W_qkv [768,2304] f32 -> Bt [2304,768] bf16 transposed
__global__ __launch_bounds__(256) void prep_w_kernel(const float* __restrict__ W,
                                                     short* __restrict__ Bt) {
  __shared__ float tile[64][65];
  int k0 = blockIdx.x * 64;
  int n0 = blockIdx.y * 64;
  int t = threadIdx.x;
#pragma unroll
  for (int it = 0; it < 16; ++it) {
    int r = it * 4 + (t >> 6);
    int c = t & 63;
    tile[r][c] = W[(size_t)(k0 + r) * 2304 + n0 + c];
  }
  __syncthreads();
#pragma unroll
  for (int it = 0; it < 16; ++it) {
    int nr = it * 4 + (t >> 6);
    int kc = t & 63;
    Bt[(size_t)(n0 + nr) * 768 + k0 + kc] = (short)f2bf(tile[kc][nr]);
  }
}

// W_proj [768,768] f32 -> Wpt [768,768] bf16 transposed
__global__ __launch_bounds__(256) void prep_wp_kernel(const float* __restrict__ W,
                                                      short* __restrict__ Bt) {
  __shared__ float tile[64][65];
  int k0 = blockIdx.x * 64;
  int n0 = blockIdx.y * 64;
  int t = threadIdx.x;
#pragma unroll
  for (int it = 0; it < 16; ++it) {
    int r = it * 4 + (t >> 6);
    int c = t & 63;
    tile[r][c] = W[(size_t)(k0 + r) * 768 + n0 + c];
  }
  __syncthreads();
#pragma unroll
  for (int it = 0; it < 16; ++it) {
    int nr = it * 4 + (t >> 6);
    int kc = t & 63;
    Bt[(size_t)(n0 + nr) * 768 + k0 + kc] = (short)f2bf(tile[kc][nr]);
  }
}

// pos [12,1024,1024] f32 -> posb bf16 (QSCALE-folded), pre-swizzled to the
// attn kernel's per-lane register order (each element consumed exactly once).
__global__ __launch_bounds__(256) void prep_pos_kernel(const float* __restrict__ P,
                                                       short* __restrict__ PB) {
  int t = blockIdx.x * 256 + threadIdx.x;   // 12<<17 = 1,572,864 threads
  int lane = t & 63;
  int jh   = (t >> 6) & 1;
  int i0   = (t >> 7) & 1;
  int w    = (t >> 8) & 3;
  int ti   = (t >> 10) & 15;
  int qblk = (t >> 14) & 7;
  int h    = t >> 17;
  int c5 = lane & 31, g1 = lane >> 5;
  int q = qblk * 128 + w * 32 + c5;
  const float* src = P + ((size_t)h * SEQ + q) * SEQ
                     + ti * 64 + i0 * 32 + 4 * g1 + 16 * jh;
  float4v v0 = *(const float4v*)(src);       // jl = 0..3  (kv +0..3)
  float4v v1 = *(const float4v*)(src + 8);   // jl = 4..7  (kv +8..11)
  union { short s[8]; bf16x8 v; } o;
#pragma unroll
  for (int p = 0; p < 4; ++p) {
    o.s[p]     = (short)f2bf(v0[p] * QSCALE);
    o.s[4 + p] = (short)f2bf(v1[p] * QSCALE);
  }
  *(bf16x8*)(PB + (size_t)t * 8) = o.v;
}

// 128x128-tile GEMM, BK=32, K=768 (24 steps), 8 waves (2 row x 4 col),
// 16x16x32 bf16 MFMA. Distance-2 counted staging over 3 LDS buffers
// (3 x 16 KB = 48 KB -> 3 blocks/CU = 6 waves/SIMD, barrier-decoupled).
// XCD-chunked linear grid. MODE 1: qkv (N=2304); MODE 2: proj (N=768).
template <int MODE>
__global__ __launch_bounds__(512, 6) void gemm_kernel(
    const short* __restrict__ A, const short* __restrict__ Bt,
    const float* __restrict__ bias,
    short* __restrict__ outQ, short* __restrict__ outK, short* __restrict__ outVT,
    float* __restrict__ outF) {
  constexpr int NBLK = (MODE == 1) ? 18 : 6;     // n-blocks per m-row
  constexpr int CHUNK = (MODE == 1) ? 144 : 48;  // nwg/8
  const int bid = blockIdx.x;
  const int lb = (bid & 7) * CHUNK + (bid >> 3); // XCD-chunked, bijective
  const int n0 = (lb % NBLK) * 128;
  const int m0 = (lb / NBLK) * 128;

  // per buffer: A 128x32 (4096 sh) + B 128x32 (4096 sh) = 16 KB
  __shared__ short lds[3 * 8192];

  const int tid = threadIdx.x;
  const int lane = tid & 63;
  const int w = tid >> 6;
  const int wr = (w & 1) * 64;       // 2 row-groups of 64
  const int wc = (w >> 1) * 32;      // 4 col-groups of 32
  const int c = lane & 15, g = lane >> 4;
  f32x4 acc[4][2];
#pragma unroll
  for (int mi = 0; mi < 4; ++mi)
#pragma unroll
    for (int ni = 0; ni < 2; ++ni) acc[mi][ni] = (f32x4){0.f, 0.f, 0.f, 0.f};

  // 2 gload_lds per thread per stage. Row r (0..127) = tid>>2, 16B unit
  // u = tid&3 within the 64B row. Linear LDS dest (wave-uniform base +
  // lane*16); inverse swizzle u^(r&3) applied on the GLOBAL source so that
  // LDS slot s of row r holds global unit s^(r&3).
  auto STAGE = [&](int buf, int k0) {
    short* base = lds + buf * 8192;
    int row = tid >> 2;
    int us = (tid & 3) ^ (row & 3);
    gload_lds16(A + (size_t)(m0 + row) * 768 + k0 + us * 8, base + w * 512);
    gload_lds16(Bt + (size_t)(n0 + row) * 768 + k0 + us * 8, base + 4096 + w * 512);
  };

  STAGE(0, 0);
  STAGE(1, 32);
  asm volatile("s_waitcnt vmcnt(2)" ::: "memory");   // stage(0) landed
  __builtin_amdgcn_sched_barrier(0);
  __builtin_amdgcn_s_barrier();

  for (int t = 0; t < 24; ++t) {
    if (t < 22) STAGE((t + 2) % 3, (t + 2) * 32);   // 2 steps in flight
    const char* Ab = (const char*)(lds + (t % 3) * 8192);
    const char* Bb = Ab + 8192;
    __builtin_amdgcn_s_setprio(1);
    bf16x8 af[4], bfv[2];
#pragma unroll
    for (int mi = 0; mi < 4; ++mi) {
      int row = wr + mi * 16 + c;
      af[mi] = *(const bf16x8*)(Ab + row * 64 + ((g ^ (row & 3)) * 16));
    }
#pragma unroll
    for (int ni = 0; ni < 2; ++ni) {
      int row = wc + ni * 16 + c;
      bfv[ni] = *(const bf16x8*)(Bb + row * 64 + ((g ^ (row & 3)) * 16));
    }
#pragma unroll
    for (int mi = 0; mi < 4; ++mi)
#pragma unroll
      for (int ni = 0; ni < 2; ++ni)
        acc[mi][ni] = __builtin_amdgcn_mfma_f32_16x16x32_bf16(
            af[mi], bfv[ni], acc[mi][ni], 0, 0, 0);
    __builtin_amdgcn_s_setprio(0);
    if (t < 23) {
      // own stage(t+1) proven landed; stage(t+2)'s 2 loads stay in flight
      if (t < 22) asm volatile("s_waitcnt vmcnt(2)" ::: "memory");
      else        asm volatile("s_waitcnt vmcnt(0)" ::: "memory");
      __builtin_amdgcn_sched_barrier(0);
      __builtin_amdgcn_s_barrier();
    }
  }

  if (MODE == 1) {
    // block-uniform third: n0 multiple of 128, 128 | 768
    const int three = n0 / 768;
    const int nb = n0 - three * 768;
#pragma unroll
    for (int mi = 0; mi < 4; ++mi)
#pragma unroll
      for (int ni = 0; ni < 2; ++ni)
#pragma unroll
        for (int j = 0; j < 4; ++j) {
          int row = m0 + wr + mi * 16 + (g << 2) + j;
          int col = n0 + wc + ni * 16 + c;
          float v = acc[mi][ni][j] + bias[col];
          int rem = nb + wc + ni * 16 + c;
          int hh = rem >> 6, d = rem & 63;
          int b = row >> 10, n = row & 1023;
          size_t bh = (size_t)(b * 12 + hh);
          if (three == 0)      outQ[(bh * 1024 + n) * 64 + d] = (short)f2bf(v * QSCALE);
          else if (three == 1) outK[(bh * 1024 + n) * 64 + d] = (short)f2bf(v);
          else                 outVT[(bh * 64 + d) * 1024 + n] = (short)f2bf(v);
        }
  } else {
#pragma unroll
    for (int mi = 0; mi < 4; ++mi)
#pragma unroll
      for (int ni = 0; ni < 2; ++ni)
#pragma unroll
        for (int j = 0; j < 4; ++j) {
          int row = m0 + wr + mi * 16 + (g << 2) + j;
          int col = n0 + wc + ni * 16 + c;
          outF[(size_t)row * 768 + col] = acc[mi][ni][j] + bias[col];
        }
  }
}

// build one PV B-frag (4 u32 = 8 bf16, k = kv) from packed P pairs:
// permlane32_swap(x=pk[m][p], y=pk[m+1][p]) -> x' = frag reg (own|swap),
// y' = frag reg (swap|own) for the two lane halves. 4 swaps per 32-kv block.
#define MKFRAG(B, pA, pB, pC, pD)                                    \
  { unsigned x0 = (pA), y0 = (pC), x1 = (pB), y1 = (pD);             \
    asm("v_permlane32_swap_b32 %0, %1" : "+v"(x0), "+v"(y0));        \
    asm("v_permlane32_swap_b32 %0, %1" : "+v"(x1), "+v"(y1));        \
    B.u[0] = x0; B.u[1] = x1; B.u[2] = y0; B.u[3] = y1; }

// Flash attention, 32x32x16 MFMA, swapped QK^T, fixed-shift softmax,
// permlane32_swap P-redistribute, distance-2 KV pipeline, coalesced
// pre-swizzled bf16 pos (QSCALE folded), h-major XCD swizzle.
// grid: 768 blocks x 256 threads; 4 waves x 32 q-rows (QBLK=128).
__global__ __launch_bounds__(256, 3) void attn_kernel(
    const short* __restrict__ qb, const short* __restrict__ kb,
    const short* __restrict__ vtb, const short* __restrict__ posb,
    short* __restrict__ outb) {
  // h-major XCD swizzle: the 8 same-(h,qblk) diff-b blocks share one XCD L2.
  const int bid = blockIdx.x;
  const int lb = (bid & 7) * 96 + (bid >> 3);
  const int qblk = lb & 7;
  const int hb = lb >> 3;            // 0..95 = h*8 + b
  const int h = hb >> 3, b = hb & 7;

  const int tid = threadIdx.x, lane = tid & 63, w = tid >> 6;
  const int c5 = lane & 31, g1 = lane >> 5;
  const size_t bh = (size_t)(b * 12 + h);
  const short* Q = qb + bh * SEQ * 64;
  const short* K = kb + bh * SEQ * 64;
  const short* VT = vtb + bh * 64 * SEQ;
  const int q0w = qblk * 128 + w * 32;

  // per-(block,wave,lane) base into pre-swizzled pos (shorts)
  const short* pwb = posb + (size_t)h * 1048576 + (size_t)qblk * 131072
                     + w * 2048 + lane * 8;

  __shared__ short kls[3 * 4096];
  __shared__ short vls[3 * 4096];

  // Q as B-operand of 32x32x16: B[k=16kd+8g1+i][col q=c5]; Q pre-scaled.
  bf16x8 qf[4];
#pragma unroll
  for (int kd = 0; kd < 4; ++kd)
    qf[kd] = *(const bf16x8*)(Q + (size_t)(q0w + c5) * 64 + kd * 16 + g1 * 8);

  f32x16 o0, o1;    // O^T: rows d = (r&3)+8*(r>>2)+4g1 (+32 for o1), col q=c5
#pragma unroll
  for (int i = 0; i < 16; ++i) { o0[i] = 0.f; o1[i] = 0.f; }
  float lsum = 0.f;

  // 4-wave STAGE: 2 K + 2 V gload_lds per thread (wave w: rows 8w..8w+7, +32)
  auto STAGE = [&](short* kb_, short* vb_, int kv0) {
    int r0 = w * 8 + (lane >> 3);
    int u0 = (lane & 7) ^ (r0 & 7);
    gload_lds16(K + (size_t)(kv0 + r0) * 64 + u0 * 8, kb_ + w * 512);
    gload_lds16(K + (size_t)(kv0 + 32 + r0) * 64 + u0 * 8, kb_ + 2048 + w * 512);
    gload_lds16(VT + (size_t)r0 * SEQ + kv0 + u0 * 8, vb_ + w * 512);
    gload_lds16(VT + (size_t)(32 + r0) * SEQ + kv0 + u0 * 8, vb_ + 2048 + w * 512);
  };

  short* kbuf0 = kls;        short* vbuf0 = vls;
  short* kbuf1 = kls + 4096; short* vbuf1 = vls + 4096;
  short* kbuf2 = kls + 8192; short* vbuf2 = vls + 8192;

  STAGE(kbuf0, vbuf0, 0);
  STAGE(kbuf1, vbuf1, 64);
  asm volatile("s_waitcnt vmcnt(4)" ::: "memory");   // stage(0) landed
  __builtin_amdgcn_sched_barrier(0);
  __builtin_amdgcn_s_barrier();

  for (int ti = 0; ti < 16; ++ti) {
    const int kv0 = ti * 64;

    // coalesced pos loads (4 x 16B, wave-dense), consumed in softmax
    union { bf16x8 v; unsigned u[4]; } ua0, ua1, ub0, ub1;
    ua0.v = *(const bf16x8*)(pwb + ti * 8192);          // i0=0, jh=0 -> r=0..7
    ua1.v = *(const bf16x8*)(pwb + ti * 8192 + 512);    // i0=0, jh=1 -> r=8..15
    ub0.v = *(const bf16x8*)(pwb + ti * 8192 + 1024);   // i0=1, jh=0
    ub1.v = *(const bf16x8*)(pwb + ti * 8192 + 1536);   // i0=1, jh=1
    asm volatile("" ::: "memory");   // pin pos-issue before STAGE
    if (ti < 14) STAGE(kbuf2, vbuf2, kv0 + 128);

    const short* kc = kbuf0;
    const short* vc = vbuf0;

    // QK^T swapped: A = K rows kv (2 blocks of 32), B = Q cols q.
    f32x16 p0, p1;
#pragma unroll
    for (int i = 0; i < 16; ++i) { p0[i] = 0.f; p1[i] = 0.f; }
    __builtin_amdgcn_s_setprio(1);
#pragma unroll
    for (int kd = 0; kd < 4; ++kd) {
      int off0 = (c5 * 128 + kd * 32 + g1 * 16) ^ ((c5 & 7) << 4);
      int off1 = ((32 + c5) * 128 + kd * 32 + g1 * 16) ^ ((c5 & 7) << 4);
      bf16x8 kf0 = *(const bf16x8*)((const char*)kc + off0);
      bf16x8 kf1 = *(const bf16x8*)((const char*)kc + off1);
      p0 = __builtin_amdgcn_mfma_f32_32x32x16_bf16(kf0, qf[kd], p0, 0, 0, 0);
      p1 = __builtin_amdgcn_mfma_f32_32x32x16_bf16(kf1, qf[kd], p1, 0, 0, 0);
    }
    __builtin_amdgcn_s_setprio(0);

    // P = exp2(qk + pos); reg r: kv = (r&3)+8*(r>>2)+4g1 (+32 for p1)
#pragma unroll
    for (int r = 0; r < 16; ++r) {
      unsigned wa = (r < 8) ? ua0.u[(r >> 1) & 3] : ua1.u[(r >> 1) & 3];
      unsigned wb = (r < 8) ? ub0.u[(r >> 1) & 3] : ub1.u[(r >> 1) & 3];
      float a = exp2f(p0[r] + bfsel(wa, r & 1));
      float bq = exp2f(p1[r] + bfsel(wb, r & 1));
      p0[r] = a; p1[r] = bq;
      lsum += a + bq;
    }

    // pack pairs along j: pk[2m+p] = (kv=8m+4g1+2p, +1)
    unsigned pk0[8], pk1[8];
#pragma unroll
    for (int m = 0; m < 4; ++m) {
      pk0[2 * m]     = cvtpk(p0[4 * m],     p0[4 * m + 1]);
      pk0[2 * m + 1] = cvtpk(p0[4 * m + 2], p0[4 * m + 3]);
      pk1[2 * m]     = cvtpk(p1[4 * m],     p1[4 * m + 1]);
      pk1[2 * m + 1] = cvtpk(p1[4 * m + 2], p1[4 * m + 3]);
    }

    // PV B-frags: step s covers kv 16s..16s+15; k = 8g1+i
    union bb { bf16x8 v; unsigned u[4]; } B0, B1, B2, B3;
    MKFRAG(B0, pk0[0], pk0[1], pk0[2], pk0[3]);   // s=0
    MKFRAG(B1, pk0[4], pk0[5], pk0[6], pk0[7]);   // s=1
    MKFRAG(B2, pk1[0], pk1[1], pk1[2], pk1[3]);   // s=2
    MKFRAG(B3, pk1[4], pk1[5], pk1[6], pk1[7]);   // s=3

    // PV: O^T += V^T (A, rows d) x P^T (B, cols q)
    __builtin_amdgcn_s_setprio(1);
#define PVSTEP(Bv, s)                                                        \
    { int o0f = (c5 * 128 + (s) * 32 + g1 * 16) ^ ((c5 & 7) << 4);           \
      int o1f = ((32 + c5) * 128 + (s) * 32 + g1 * 16) ^ ((c5 & 7) << 4);    \
      bf16x8 vf0 = *(const bf16x8*)((const char*)vc + o0f);                  \
      bf16x8 vf1 = *(const bf16x8*)((const char*)vc + o1f);                  \
      o0 = __builtin_amdgcn_mfma_f32_32x32x16_bf16(vf0, Bv.v, o0, 0, 0, 0);  \
      o1 = __builtin_amdgcn_mfma_f32_32x32x16_bf16(vf1, Bv.v, o1, 0, 0, 0); }
    PVSTEP(B0, 0); PVSTEP(B1, 1); PVSTEP(B2, 2); PVSTEP(B3, 3);
#undef PVSTEP
    __builtin_amdgcn_s_setprio(0);

    // rotate buffers
    short* tk = kbuf0; kbuf0 = kbuf1; kbuf1 = kbuf2; kbuf2 = tk;
    short* tv = vbuf0; vbuf0 = vbuf1; vbuf1 = vbuf2; vbuf2 = tv;

    // pos consumed above -> only stage(ti+2)[4] may remain in flight.
    if (ti < 15) {
      if (ti < 14) asm volatile("s_waitcnt vmcnt(4)" ::: "memory");
      else         asm volatile("s_waitcnt vmcnt(0)" ::: "memory");
      __builtin_amdgcn_sched_barrier(0);
      __builtin_amdgcn_s_barrier();
    }
  }

  // lane and lane^32 hold complementary kv rows of the same q-column
  lsum += __shfl_xor(lsum, 32);
  float inv = 1.0f / lsum;
  size_t obase = (size_t)(b * SEQ + q0w + c5) * 768 + h * 64 + g1 * 4;
#pragma unroll
  for (int m = 0; m < 4; ++m) {
    short4v ov0, ov1;
#pragma unroll
    for (int j = 0; j < 4; ++j) {
      ov0[j] = (short)f2bf(o0[4 * m + j] * inv);
      ov1[j] = (short)f2bf(o1[4 * m + j] * inv);
    }
    *(short4v*)(outb + obase + m * 8) = ov0;
    *(short4v*)(outb + obase + 32 + m * 8) = ov1;
  }
}

extern "C" void kernel_launch(void* const* d_in, const int* in_sizes, int n_in,
                              void* d_out, int out_size, void* d_ws, size_t ws_size,
                              hipStream_t stream) {
  const float* x      = (const float*)d_in[0];
  const float* pos    = (const float*)d_in[1];
  const float* W_qkv  = (const float*)d_in[2];
  const float* b_qkv  = (const float*)d_in[3];
  const float* W_proj = (const float*)d_in[4];
  const float* b_proj = (const float*)d_in[5];
  float* out = (float*)d_out;

  char* ws = (char*)d_ws;
  short* A       = (short*)(ws);                  // 12,582,912 (consumed by gemm<1>)
  short* attnbuf = (short*)(ws);                  // alias of A (written after)
  short* Bt      = (short*)(ws + 12582912);       //  3,538,944
  short* wpt     = (short*)(ws + 16121856);       //  1,179,648
  short* qbuf    = (short*)(ws + 17301504);       // 12,582,912
  short* kbuf    = (short*)(ws + 29884416);       // 12,582,912
  short* vtbuf   = (short*)(ws + 42467328);       // 12,582,912
  short* posb    = (short*)(ws + 55050240);       // 25,165,824
  // total: 80,216,064 bytes

  prep_x_kernel<<<6144, 256, 0, stream>>>(x, A);
  prep_w_kernel<<<dim3(12, 36), 256, 0, stream>>>(W_qkv, Bt);
  prep_wp_kernel<<<dim3(12, 12), 256, 0, stream>>>(W_proj, wpt);
  prep_pos_kernel<<<6144, 256, 0, stream>>>(pos, posb);
  gemm_kernel<1><<<1152, 512, 0, stream>>>(A, Bt, b_qkv,
                                           qbuf, kbuf, vtbuf, nullptr);
  attn_kernel<<<768, 256, 0, stream>>>(qbuf, kbuf, vtbuf, posb, attnbuf);
  gemm_kernel<2><<<384, 512, 0, stream>>>(attnbuf, wpt, b_proj,
                                          nullptr, nullptr, nullptr, out);
}